// Round 10
// baseline (134.686 us; speedup 1.0000x reference)
//
#include <hip/hip_runtime.h>
#include <math.h>

// DotProductAttention B=64,S=1024,D=64 fp32, bf16-MFMA flash attention.
// Round 12: latency-stall attack on two axes. Seven data points show dur
// invariant (~52-54us) to block count, iters/block, mapping, HBM traffic,
// barrier count, LDS traffic (-50%), VMEM count (-50%) -> active CUs are
// stall-bound on the per-iteration serial chain (ds_read->MFMA->fmax->
// 2 dependent shfls->exp2->pack->MFMA + 2 barriers) with too few
// independent streams (2-4 blocks/CU) to hide it.
//  1) MORE STREAMS: lean (P-in-reg) kernel + split-K 2-way -> 2048 blocks
//     = 8 blocks/CU co-resident (LDS 18.4KB, VGPR ~60 <= 64 -> 8 w/SIMD).
//     r3/r5 split-K nulls were with the HEAVY kernel (Ps round-trip).
//  2) SHORTER CHAIN: common softmax path has ZERO cross-lane ops:
//     - defer-rescale predicate uses LANE-LOCAL max (equivalent: __all over
//       lanes of local-max<=thr <=> all row maxes<=thr); the 2 dependent
//       max-shfls move into the rare rescale branch.
//     - l-reduction DEFERRED to epilogue: per-lane partial l_run (alpha is
//       row-uniform so partial scaling is exact); 2 shfls once, not per iter.
// Kept: P-in-reg slot perm (r7), THR=8 defer (r7), lgkm-only barrier B (r8),
// skewed decode (r5), direct-write vl<=512 / combine kernel (r3/r5 proven).
// No fences/atomics (r4 lesson).

#define BATCH 64
#define SEQ   1024
#define DIM   64
#define BQ    64           // queries per block (4 waves x 16)
#define BC    64           // keys per iteration
#define NKT   (SEQ / BC)   // 16
#define HALFT 8            // K-tiles per split-K item
#define LSTR  72           // LDS row stride in bf16 (144 B)
#define QSCALE 0.18033688011112442f   // 0.125 * log2(e)
#define MASKED -1.0e6f
#define THR    8.0f        // defer-rescale threshold (exp2 domain)

// workspace layout
#define WS_LM_SZ   (2048 * 64 * 8)              // float2 (m,l) per query per item
#define WS_O_OFF   WS_LM_SZ
#define WS_O_SZ    (2048 * 4096 * 4)            // 32 MB partial O
#define WS_NEEDED  ((size_t)WS_O_OFF + (size_t)WS_O_SZ)

typedef __attribute__((ext_vector_type(8))) short bf16x8;
typedef __attribute__((ext_vector_type(4))) float f32x4;

__device__ __forceinline__ uint pack2_trunc(float lo, float hi) {
    return __builtin_amdgcn_perm(__float_as_uint(hi), __float_as_uint(lo), 0x07060302);
}
__device__ __forceinline__ ushort f2bf_rne(float x) {
    uint u = __float_as_uint(x);
    return (ushort)((u + 0x7fffu + ((u >> 16) & 1u)) >> 16);
}

__global__ __launch_bounds__(256, 4) void attn_splitk_lean(
    const float* __restrict__ q, const float* __restrict__ k,
    const float* __restrict__ v, const int* __restrict__ valid_lens,
    float* __restrict__ out,
    float2* __restrict__ lmbuf, float* __restrict__ opart)
{
    __shared__ ushort Ks[BC * LSTR];   // [key][d]
    __shared__ ushort Vt[DIM * LSTR];  // [d][slot]  (slot = permuted key)

    const int t    = threadIdx.x;
    const int wave = t >> 6;
    const int wl   = t & 63;
    const int QD   = wl >> 4;          // quad 0..3
    const int li   = wl & 15;          // lane-in-quad 0..15
    // skewed decode (r5): co-resident blocks hit different batches
    const int g    = blockIdx.x;
    const int grp  = g >> 6;           // 0..31 = (qt<<1)|half
    const int b    = ((g & 63) + grp) & 63;
    const int half = grp & 1;
    const int qt   = grp >> 1;
    const int q0   = qt * BQ;
    const int pid  = (qt << 6) | b;
    const int item = pid * 2 + half;
    const int vl   = valid_lens[b];

    const size_t boff = (size_t)b * SEQ * DIM;

    const int it_full  = (vl == 0) ? NKT : ((vl + BC - 1) >> 6);
    const int it_begin = half * HALFT;
    const int it_end   = min(it_full, it_begin + HALFT);
    if (it_begin >= it_end) return;    // empty second half: partner direct-writes

    const bool direct = (half == 0) && (it_full <= HALFT);

    // ---- Q fragments (B-operand), pre-scaled, in registers ----
    bf16x8 qb[2];
    {
        const float* qrow = q + boff + (size_t)(q0 + wave * 16 + li) * DIM + QD * 8;
        #pragma unroll
        for (int kc = 0; kc < 2; kc++) {
            float4 a = *(const float4*)(qrow + kc * 32);
            float4 c = *(const float4*)(qrow + kc * 32 + 4);
            union { bf16x8 v; ushort u[8]; } tmp;
            tmp.u[0] = f2bf_rne(a.x * QSCALE);
            tmp.u[1] = f2bf_rne(a.y * QSCALE);
            tmp.u[2] = f2bf_rne(a.z * QSCALE);
            tmp.u[3] = f2bf_rne(a.w * QSCALE);
            tmp.u[4] = f2bf_rne(c.x * QSCALE);
            tmp.u[5] = f2bf_rne(c.y * QSCALE);
            tmp.u[6] = f2bf_rne(c.z * QSCALE);
            tmp.u[7] = f2bf_rne(c.w * QSCALE);
            qb[kc] = tmp.v;
        }
    }

    // ---- prefetch registers ----
    float4 kf[4];
    float  vf[2][8];

    // V slot permutation (r7): slot ko*8+j holds key kb+((j>>2)<<5)+(j&3),
    // kb = (ko>>2)*16 + (ko&3)*4
    auto load_tile = [&](int it) {
        const float4* kg = (const float4*)(k + boff + (size_t)it * BC * DIM);
        #pragma unroll
        for (int i = 0; i < 4; i++) kf[i] = kg[t + 256 * i];
        const float* vgf = v + boff + (size_t)it * BC * DIM;
        #pragma unroll
        for (int i = 0; i < 2; i++) {
            int slot = t + 256 * i;
            int d = slot & 63, ko = slot >> 6;
            int kb = (ko >> 2) * 16 + (ko & 3) * 4;
            #pragma unroll
            for (int j = 0; j < 8; j++) {
                int kk = kb + ((j >> 2) << 5) + (j & 3);
                vf[i][j] = vgf[(size_t)kk * DIM + d];
            }
        }
    };

    auto stage = [&]() {
        #pragma unroll
        for (int i = 0; i < 4; i++) {
            int idx = t + 256 * i;
            int row = idx >> 4, c4 = idx & 15;
            uint2 w;
            w.x = pack2_trunc(kf[i].x, kf[i].y);
            w.y = pack2_trunc(kf[i].z, kf[i].w);
            *(uint2*)&Ks[row * LSTR + c4 * 4] = w;
        }
        #pragma unroll
        for (int i = 0; i < 2; i++) {
            int slot = t + 256 * i;
            int d = slot & 63, ko = slot >> 6;
            uint4 w;
            w.x = pack2_trunc(vf[i][0], vf[i][1]);
            w.y = pack2_trunc(vf[i][2], vf[i][3]);
            w.z = pack2_trunc(vf[i][4], vf[i][5]);
            w.w = pack2_trunc(vf[i][6], vf[i][7]);
            *(uint4*)&Vt[d * LSTR + ko * 8] = w;
        }
    };

    float m_run = -INFINITY;
    float l_run = 0.f;                 // PER-LANE PARTIAL (reduced in epilogue)
    f32x4 acc[4];
    #pragma unroll
    for (int dt = 0; dt < 4; dt++) acc[dt] = (f32x4){0.f, 0.f, 0.f, 0.f};

    load_tile(it_begin);

    for (int it = it_begin; it < it_end; it++) {
        __builtin_amdgcn_sched_barrier(0);
        __builtin_amdgcn_s_barrier();          // A: prior tile's reads done
        __builtin_amdgcn_sched_barrier(0);

        stage();
        if (it + 1 < it_end) load_tile(it + 1);    // vmcnt floats across B

        __builtin_amdgcn_sched_barrier(0);
        asm volatile("s_waitcnt lgkmcnt(0)" ::: "memory");
        __builtin_amdgcn_s_barrier();          // B: staging visible (lgkm only)
        __builtin_amdgcn_sched_barrier(0);

        // ---- S^T = K x Q^T ----
        f32x4 sc[4];
        #pragma unroll
        for (int kt = 0; kt < 4; kt++) {
            bf16x8 ka0 = *(const bf16x8*)&Ks[(kt * 16 + li) * LSTR + QD * 8];
            bf16x8 ka1 = *(const bf16x8*)&Ks[(kt * 16 + li) * LSTR + 32 + QD * 8];
            f32x4 c = (f32x4){0.f, 0.f, 0.f, 0.f};
            c = __builtin_amdgcn_mfma_f32_16x16x32_bf16(ka0, qb[0], c, 0, 0, 0);
            c = __builtin_amdgcn_mfma_f32_16x16x32_bf16(ka1, qb[1], c, 0, 0, 0);
            sc[kt] = c;
        }

        // ---- mask ----
        const int kbase = it * BC;
        if (kbase + BC > vl) {
            #pragma unroll
            for (int kt = 0; kt < 4; kt++)
                #pragma unroll
                for (int r = 0; r < 4; r++) {
                    int key = kbase + kt * 16 + QD * 4 + r;
                    if (key >= vl) sc[kt][r] = MASKED;
                }
        }

        // ---- softmax: common path has ZERO cross-lane ops ----
        float mt = -INFINITY;                       // lane-local max
        #pragma unroll
        for (int kt = 0; kt < 4; kt++)
            #pragma unroll
            for (int r = 0; r < 4; r++) mt = fmaxf(mt, sc[kt][r]);

        if (!__all(mt - m_run <= THR)) {
            // rare rescale branch: full reduce + row-uniform alpha
            mt = fmaxf(mt, __shfl_xor(mt, 16, 64));
            mt = fmaxf(mt, __shfl_xor(mt, 32, 64));
            float mn = fmaxf(m_run, mt);
            float alpha = exp2f(m_run - mn);        // -inf first tile -> 0
            m_run = mn;
            l_run *= alpha;                         // per-lane partial scales exactly
            float a0 = __shfl(alpha, QD * 4 + 0, 64);
            float a1 = __shfl(alpha, QD * 4 + 1, 64);
            float a2 = __shfl(alpha, QD * 4 + 2, 64);
            float a3 = __shfl(alpha, QD * 4 + 3, 64);
            #pragma unroll
            for (int dt = 0; dt < 4; dt++) {
                acc[dt][0] *= a0; acc[dt][1] *= a1;
                acc[dt][2] *= a2; acc[dt][3] *= a3;
            }
        }

        // P in registers (slot permutation, r7): pa0 = sc0,sc2; pa1 = sc1,sc3
        union { bf16x8 v; uint u[4]; } pa0u, pa1u;
        {
            float p00 = exp2f(sc[0][0] - m_run), p01 = exp2f(sc[0][1] - m_run);
            float p02 = exp2f(sc[0][2] - m_run), p03 = exp2f(sc[0][3] - m_run);
            float p10 = exp2f(sc[1][0] - m_run), p11 = exp2f(sc[1][1] - m_run);
            float p12 = exp2f(sc[1][2] - m_run), p13 = exp2f(sc[1][3] - m_run);
            float p20 = exp2f(sc[2][0] - m_run), p21 = exp2f(sc[2][1] - m_run);
            float p22 = exp2f(sc[2][2] - m_run), p23 = exp2f(sc[2][3] - m_run);
            float p30 = exp2f(sc[3][0] - m_run), p31 = exp2f(sc[3][1] - m_run);
            float p32 = exp2f(sc[3][2] - m_run), p33 = exp2f(sc[3][3] - m_run);
            l_run += ((p00 + p01) + (p02 + p03)) + ((p10 + p11) + (p12 + p13))
                   + ((p20 + p21) + (p22 + p23)) + ((p30 + p31) + (p32 + p33));
            pa0u.u[0] = pack2_trunc(p00, p01);
            pa0u.u[1] = pack2_trunc(p02, p03);
            pa0u.u[2] = pack2_trunc(p20, p21);
            pa0u.u[3] = pack2_trunc(p22, p23);
            pa1u.u[0] = pack2_trunc(p10, p11);
            pa1u.u[1] = pack2_trunc(p12, p13);
            pa1u.u[2] = pack2_trunc(p30, p31);
            pa1u.u[3] = pack2_trunc(p32, p33);
        }

        // ---- PV: O += P x V(slot-permuted) ----
        #pragma unroll
        for (int dt = 0; dt < 4; dt++) {
            bf16x8 vb0 = *(const bf16x8*)&Vt[(dt * 16 + li) * LSTR + QD * 8];
            bf16x8 vb1 = *(const bf16x8*)&Vt[(dt * 16 + li) * LSTR + 32 + QD * 8];
            acc[dt] = __builtin_amdgcn_mfma_f32_16x16x32_bf16(pa0u.v, vb0, acc[dt], 0, 0, 0);
            acc[dt] = __builtin_amdgcn_mfma_f32_16x16x32_bf16(pa1u.v, vb1, acc[dt], 0, 0, 0);
        }
    }

    // ---- deferred l reduction (once) ----
    l_run += __shfl_xor(l_run, 16, 64);
    l_run += __shfl_xor(l_run, 32, 64);

    if (direct) {
        float invl = 1.0f / l_run;
        float i0 = __shfl(invl, QD * 4 + 0, 64);
        float i1 = __shfl(invl, QD * 4 + 1, 64);
        float i2 = __shfl(invl, QD * 4 + 2, 64);
        float i3 = __shfl(invl, QD * 4 + 3, 64);
        float* ob = out + boff + (size_t)q0 * DIM;
        const int rbase = wave * 16 + QD * 4;
        #pragma unroll
        for (int dt = 0; dt < 4; dt++) {
            int col = dt * 16 + li;
            ob[(size_t)(rbase + 0) * DIM + col] = acc[dt][0] * i0;
            ob[(size_t)(rbase + 1) * DIM + col] = acc[dt][1] * i1;
            ob[(size_t)(rbase + 2) * DIM + col] = acc[dt][2] * i2;
            ob[(size_t)(rbase + 3) * DIM + col] = acc[dt][3] * i3;
        }
    } else {
        if (QD == 0)
            lmbuf[(size_t)item * 64 + wave * 16 + li] = make_float2(m_run, l_run);
        float* ob = opart + (size_t)item * (BQ * DIM);
        const int rbase = wave * 16 + QD * 4;
        #pragma unroll
        for (int dt = 0; dt < 4; dt++) {
            int col = dt * 16 + li;
            ob[(size_t)(rbase + 0) * DIM + col] = acc[dt][0];
            ob[(size_t)(rbase + 1) * DIM + col] = acc[dt][1];
            ob[(size_t)(rbase + 2) * DIM + col] = acc[dt][2];
            ob[(size_t)(rbase + 3) * DIM + col] = acc[dt][3];
        }
    }
}

// ---- kernel 2: combine halves of pairs with it_full > HALFT (r5 proven) ----
__global__ __launch_bounds__(256) void attn_combine(
    const int* __restrict__ valid_lens,
    const float2* __restrict__ lmbuf, const float* __restrict__ opart,
    float* __restrict__ out)
{
    const int pid = blockIdx.x;
    const int b   = pid & 63;
    const int qt  = pid >> 6;
    const int vl  = valid_lens[b];
    const int it_full = (vl == 0) ? NKT : ((vl + BC - 1) >> 6);
    if (it_full <= HALFT) return;

    const int t  = threadIdx.x;
    const int qr = t >> 2;
    const int c4 = t & 3;
    const int i1 = pid * 2;

    float2 ml1 = lmbuf[(size_t)i1 * 64 + qr];
    float2 ml2 = lmbuf[(size_t)(i1 + 1) * 64 + qr];
    float M  = fmaxf(ml1.x, ml2.x);
    float w1 = exp2f(ml1.x - M);
    float w2 = exp2f(ml2.x - M);
    float inv = 1.f / (ml1.y * w1 + ml2.y * w2);
    w1 *= inv; w2 *= inv;

    const float4* o1 = (const float4*)(opart + (size_t)i1 * (BQ * DIM));
    const float4* o2 = (const float4*)(opart + (size_t)(i1 + 1) * (BQ * DIM));
    float4* ob = (float4*)(out + ((size_t)b * SEQ + (size_t)qt * BQ) * DIM);
    #pragma unroll
    for (int j = 0; j < 4; j++) {
        int idx = qr * 16 + j * 4 + c4;
        float4 a  = o1[idx];
        float4 bb = o2[idx];
        float4 r;
        r.x = a.x * w1 + bb.x * w2;
        r.y = a.y * w1 + bb.y * w2;
        r.z = a.z * w1 + bb.z * w2;
        r.w = a.w * w1 + bb.w * w2;
        ob[idx] = r;
    }
}

// ---------------- fallback (no workspace): r7 proven single kernel ----------------
__global__ __launch_bounds__(256, 4) void attn_mfma_flash4(
    const float* __restrict__ q, const float* __restrict__ k,
    const float* __restrict__ v, const int* __restrict__ valid_lens,
    float* __restrict__ out)
{
    __shared__ ushort Ks[BC * LSTR];
    __shared__ ushort Vt[DIM * LSTR];

    const int t    = threadIdx.x;
    const int wave = t >> 6;
    const int wl   = t & 63;
    const int QD   = wl >> 4;
    const int li   = wl & 15;
    const int b    = blockIdx.x & 63;
    const int q0   = (blockIdx.x >> 6) * BQ;
    const int vl   = valid_lens[b];

    const size_t boff = (size_t)b * SEQ * DIM;

    bf16x8 qb[2];
    {
        const float* qrow = q + boff + (size_t)(q0 + wave * 16 + li) * DIM + QD * 8;
        #pragma unroll
        for (int kc = 0; kc < 2; kc++) {
            float4 a = *(const float4*)(qrow + kc * 32);
            float4 c = *(const float4*)(qrow + kc * 32 + 4);
            union { bf16x8 v; ushort u[8]; } tmp;
            tmp.u[0] = f2bf_rne(a.x * QSCALE);
            tmp.u[1] = f2bf_rne(a.y * QSCALE);
            tmp.u[2] = f2bf_rne(a.z * QSCALE);
            tmp.u[3] = f2bf_rne(a.w * QSCALE);
            tmp.u[4] = f2bf_rne(c.x * QSCALE);
            tmp.u[5] = f2bf_rne(c.y * QSCALE);
            tmp.u[6] = f2bf_rne(c.z * QSCALE);
            tmp.u[7] = f2bf_rne(c.w * QSCALE);
            qb[kc] = tmp.v;
        }
    }

    const int it_max = (vl == 0) ? NKT : ((vl + BC - 1) >> 6);

    float4 kf[4];
    float  vf[2][8];

    auto load_tile = [&](int it) {
        const float4* kg = (const float4*)(k + boff + (size_t)it * BC * DIM);
        #pragma unroll
        for (int i = 0; i < 4; i++) kf[i] = kg[t + 256 * i];
        const float* vgf = v + boff + (size_t)it * BC * DIM;
        #pragma unroll
        for (int i = 0; i < 2; i++) {
            int slot = t + 256 * i;
            int d = slot & 63, ko = slot >> 6;
            int kb = (ko >> 2) * 16 + (ko & 3) * 4;
            #pragma unroll
            for (int j = 0; j < 8; j++) {
                int kk = kb + ((j >> 2) << 5) + (j & 3);
                vf[i][j] = vgf[(size_t)kk * DIM + d];
            }
        }
    };

    auto stage = [&]() {
        #pragma unroll
        for (int i = 0; i < 4; i++) {
            int idx = t + 256 * i;
            int row = idx >> 4, c4 = idx & 15;
            uint2 w;
            w.x = pack2_trunc(kf[i].x, kf[i].y);
            w.y = pack2_trunc(kf[i].z, kf[i].w);
            *(uint2*)&Ks[row * LSTR + c4 * 4] = w;
        }
        #pragma unroll
        for (int i = 0; i < 2; i++) {
            int slot = t + 256 * i;
            int d = slot & 63, ko = slot >> 6;
            uint4 w;
            w.x = pack2_trunc(vf[i][0], vf[i][1]);
            w.y = pack2_trunc(vf[i][2], vf[i][3]);
            w.z = pack2_trunc(vf[i][4], vf[i][5]);
            w.w = pack2_trunc(vf[i][6], vf[i][7]);
            *(uint4*)&Vt[d * LSTR + ko * 8] = w;
        }
    };

    float m_run = -INFINITY, l_run = 0.f;
    f32x4 acc[4];
    #pragma unroll
    for (int dt = 0; dt < 4; dt++) acc[dt] = (f32x4){0.f, 0.f, 0.f, 0.f};

    load_tile(0);

    for (int it = 0; it < it_max; it++) {
        __builtin_amdgcn_sched_barrier(0);
        __builtin_amdgcn_s_barrier();
        __builtin_amdgcn_sched_barrier(0);

        stage();
        if (it + 1 < it_max) load_tile(it + 1);

        __builtin_amdgcn_sched_barrier(0);
        asm volatile("s_waitcnt lgkmcnt(0)" ::: "memory");
        __builtin_amdgcn_s_barrier();
        __builtin_amdgcn_sched_barrier(0);

        f32x4 sc[4];
        #pragma unroll
        for (int kt = 0; kt < 4; kt++) {
            bf16x8 ka0 = *(const bf16x8*)&Ks[(kt * 16 + li) * LSTR + QD * 8];
            bf16x8 ka1 = *(const bf16x8*)&Ks[(kt * 16 + li) * LSTR + 32 + QD * 8];
            f32x4 c = (f32x4){0.f, 0.f, 0.f, 0.f};
            c = __builtin_amdgcn_mfma_f32_16x16x32_bf16(ka0, qb[0], c, 0, 0, 0);
            c = __builtin_amdgcn_mfma_f32_16x16x32_bf16(ka1, qb[1], c, 0, 0, 0);
            sc[kt] = c;
        }

        const int kbase = it * BC;
        if (kbase + BC > vl) {
            #pragma unroll
            for (int kt = 0; kt < 4; kt++)
                #pragma unroll
                for (int r = 0; r < 4; r++) {
                    int key = kbase + kt * 16 + QD * 4 + r;
                    if (key >= vl) sc[kt][r] = MASKED;
                }
        }

        float mt = -INFINITY;
        #pragma unroll
        for (int kt = 0; kt < 4; kt++)
            #pragma unroll
            for (int r = 0; r < 4; r++) mt = fmaxf(mt, sc[kt][r]);

        if (!__all(mt - m_run <= THR)) {
            mt = fmaxf(mt, __shfl_xor(mt, 16, 64));
            mt = fmaxf(mt, __shfl_xor(mt, 32, 64));
            float mn = fmaxf(m_run, mt);
            float alpha = exp2f(m_run - mn);
            m_run = mn;
            l_run *= alpha;
            float a0 = __shfl(alpha, QD * 4 + 0, 64);
            float a1 = __shfl(alpha, QD * 4 + 1, 64);
            float a2 = __shfl(alpha, QD * 4 + 2, 64);
            float a3 = __shfl(alpha, QD * 4 + 3, 64);
            #pragma unroll
            for (int dt = 0; dt < 4; dt++) {
                acc[dt][0] *= a0; acc[dt][1] *= a1;
                acc[dt][2] *= a2; acc[dt][3] *= a3;
            }
        }

        union { bf16x8 v; uint u[4]; } pa0u, pa1u;
        {
            float p00 = exp2f(sc[0][0] - m_run), p01 = exp2f(sc[0][1] - m_run);
            float p02 = exp2f(sc[0][2] - m_run), p03 = exp2f(sc[0][3] - m_run);
            float p10 = exp2f(sc[1][0] - m_run), p11 = exp2f(sc[1][1] - m_run);
            float p12 = exp2f(sc[1][2] - m_run), p13 = exp2f(sc[1][3] - m_run);
            float p20 = exp2f(sc[2][0] - m_run), p21 = exp2f(sc[2][1] - m_run);
            float p22 = exp2f(sc[2][2] - m_run), p23 = exp2f(sc[2][3] - m_run);
            float p30 = exp2f(sc[3][0] - m_run), p31 = exp2f(sc[3][1] - m_run);
            float p32 = exp2f(sc[3][2] - m_run), p33 = exp2f(sc[3][3] - m_run);
            l_run += ((p00 + p01) + (p02 + p03)) + ((p10 + p11) + (p12 + p13))
                   + ((p20 + p21) + (p22 + p23)) + ((p30 + p31) + (p32 + p33));
            pa0u.u[0] = pack2_trunc(p00, p01);
            pa0u.u[1] = pack2_trunc(p02, p03);
            pa0u.u[2] = pack2_trunc(p20, p21);
            pa0u.u[3] = pack2_trunc(p22, p23);
            pa1u.u[0] = pack2_trunc(p10, p11);
            pa1u.u[1] = pack2_trunc(p12, p13);
            pa1u.u[2] = pack2_trunc(p30, p31);
            pa1u.u[3] = pack2_trunc(p32, p33);
        }

        #pragma unroll
        for (int dt = 0; dt < 4; dt++) {
            bf16x8 vb0 = *(const bf16x8*)&Vt[(dt * 16 + li) * LSTR + QD * 8];
            bf16x8 vb1 = *(const bf16x8*)&Vt[(dt * 16 + li) * LSTR + 32 + QD * 8];
            acc[dt] = __builtin_amdgcn_mfma_f32_16x16x32_bf16(pa0u.v, vb0, acc[dt], 0, 0, 0);
            acc[dt] = __builtin_amdgcn_mfma_f32_16x16x32_bf16(pa1u.v, vb1, acc[dt], 0, 0, 0);
        }
    }

    l_run += __shfl_xor(l_run, 16, 64);
    l_run += __shfl_xor(l_run, 32, 64);
    float invl = 1.0f / l_run;
    float i0 = __shfl(invl, QD * 4 + 0, 64);
    float i1 = __shfl(invl, QD * 4 + 1, 64);
    float i2 = __shfl(invl, QD * 4 + 2, 64);
    float i3 = __shfl(invl, QD * 4 + 3, 64);
    float* ob = out + boff + (size_t)q0 * DIM;
    const int rbase = wave * 16 + QD * 4;
    #pragma unroll
    for (int dt = 0; dt < 4; dt++) {
        int col = dt * 16 + li;
        ob[(size_t)(rbase + 0) * DIM + col] = acc[dt][0] * i0;
        ob[(size_t)(rbase + 1) * DIM + col] = acc[dt][1] * i1;
        ob[(size_t)(rbase + 2) * DIM + col] = acc[dt][2] * i2;
        ob[(size_t)(rbase + 3) * DIM + col] = acc[dt][3] * i3;
    }
}

extern "C" void kernel_launch(void* const* d_in, const int* in_sizes, int n_in,
                              void* d_out, int out_size, void* d_ws, size_t ws_size,
                              hipStream_t stream) {
    const float* q = (const float*)d_in[0];
    const float* k = (const float*)d_in[1];
    const float* v = (const float*)d_in[2];
    const int* valid_lens = (const int*)d_in[3];
    float* out = (float*)d_out;

    if (d_ws != nullptr && ws_size >= WS_NEEDED) {
        float2* lmbuf = (float2*)d_ws;
        float*  opart = (float*)((char*)d_ws + WS_O_OFF);
        attn_splitk_lean<<<dim3(BATCH * (SEQ / BQ) * 2), dim3(256), 0, stream>>>(
            q, k, v, valid_lens, out, lmbuf, opart);
        attn_combine<<<dim3(BATCH * (SEQ / BQ)), dim3(256), 0, stream>>>(
            valid_lens, lmbuf, opart, out);
    } else {
        attn_mfma_flash4<<<dim3(BATCH * (SEQ / BQ)), dim3(256), 0, stream>>>(
            q, k, v, valid_lens, out);
    }
}

// Round 11
// 134.625 us; speedup vs baseline: 1.0004x; 1.0004x over previous
//
#include <hip/hip_runtime.h>
#include <math.h>

// DotProductAttention B=64,S=1024,D=64 fp32, bf16-MFMA flash attention.
// Round 13: fuse split-K into the block. Round-12 proved the latency theory:
// 8 streams/CU + cross-lane-free softmax = 52->46.2us main kernel. But the
// two-dispatch combine structure costs ~16us (combine kernel + extra dispatch
// + 26MB partial round-trip) -> total 134.7 vs single-kernel best 124.4.
// This round keeps the 46us execution profile and deletes the plumbing:
//   - 512-thread block = TWO 4-wave groups; group g owns interleaved K-tiles
//     {g, g+2, ...} of the same (batch, q-tile) with PRIVATE K/V LDS buffers
//     (2 x 18.4KB = 36.9KB -> 4 blocks/CU = 32 waves/CU = 8 pipelines/CU,
//     same stream count as round 12's winner).
//   - Iteration counts differ by <=1 (it_full block-uniform): inactive group
//     skips work but hits every barrier -> barrier-uniform.
//   - Final merge IN-BLOCK: group 1 writes (m,l,acc) to the dead LDS (17.4KB),
//     one barrier, group 0 merges (exact 2-way flash merge; empty-group case
//     degenerates via exp2(-inf)=0) and writes out. No workspace, no combine
//     dispatch, no partial-O HBM traffic.
// Kept: P-in-reg slot perm (r9), lane-local defer predicate + deferred
// l-reduction (r12), THR=8, lgkm-only barrier B (r8), skewed decode (r6).
// launch_bounds(512,4) NOT (·,8): round-1 lesson — hard 8-waves/EU bound
// forced 32 VGPR + full spill; natural allocation of this body is ~64.

#define BATCH 64
#define SEQ   1024
#define DIM   64
#define BQ    64           // queries per block (each wave-group: 4 waves x 16)
#define BC    64           // keys per K-tile
#define NKT   (SEQ / BC)   // 16
#define LSTR  72           // LDS row stride in bf16 (144 B)
#define QSCALE 0.18033688011112442f   // 0.125 * log2(e)
#define MASKED -1.0e6f
#define THR    8.0f        // defer-rescale threshold (exp2 domain)
#define KVSZ   (BC * LSTR) // 4608 ushorts per buffer (Ks or Vt)

typedef __attribute__((ext_vector_type(8))) short bf16x8;
typedef __attribute__((ext_vector_type(4))) float f32x4;

__device__ __forceinline__ uint pack2_trunc(float lo, float hi) {
    return __builtin_amdgcn_perm(__float_as_uint(hi), __float_as_uint(lo), 0x07060302);
}
__device__ __forceinline__ ushort f2bf_rne(float x) {
    uint u = __float_as_uint(x);
    return (ushort)((u + 0x7fffu + ((u >> 16) & 1u)) >> 16);
}

__global__ __launch_bounds__(512, 4) void attn_dualgrp(
    const float* __restrict__ q, const float* __restrict__ k,
    const float* __restrict__ v, const int* __restrict__ valid_lens,
    float* __restrict__ out)
{
    // 2 groups x (Ks + Vt) = 4 x 4608 ushorts = 36864 B
    __shared__ ushort SB[4 * KVSZ];

    const int t    = threadIdx.x;
    const int wave = t >> 6;
    const int gid  = wave >> 2;        // wave-group 0/1
    const int wg   = wave & 3;         // wave within group
    const int wl   = t & 63;
    const int QD   = wl >> 4;          // quad 0..3
    const int li   = wl & 15;          // lane-in-quad 0..15
    const int tg   = t & 255;          // thread within group (groups contiguous)

    // skewed decode (r6): co-resident blocks (spacing 256 -> grp+4) hit
    // different batches -> per-CU vl mix balanced.
    const int g    = blockIdx.x;
    const int grp  = g >> 6;                  // 0..15 q-tile
    const int b    = ((g & 63) + grp) & 63;   // de-aliased batch
    const int q0   = grp * BQ;
    const int vl   = valid_lens[b];

    const size_t boff = (size_t)b * SEQ * DIM;

    ushort* Ksg = SB + gid * (2 * KVSZ);
    ushort* Vtg = Ksg + KVSZ;

    // ---- Q fragments (both groups: SAME 64 queries), pre-scaled ----
    bf16x8 qb[2];
    {
        const float* qrow = q + boff + (size_t)(q0 + wg * 16 + li) * DIM + QD * 8;
        #pragma unroll
        for (int kc = 0; kc < 2; kc++) {
            float4 a = *(const float4*)(qrow + kc * 32);
            float4 c = *(const float4*)(qrow + kc * 32 + 4);
            union { bf16x8 v; ushort u[8]; } tmp;
            tmp.u[0] = f2bf_rne(a.x * QSCALE);
            tmp.u[1] = f2bf_rne(a.y * QSCALE);
            tmp.u[2] = f2bf_rne(a.z * QSCALE);
            tmp.u[3] = f2bf_rne(a.w * QSCALE);
            tmp.u[4] = f2bf_rne(c.x * QSCALE);
            tmp.u[5] = f2bf_rne(c.y * QSCALE);
            tmp.u[6] = f2bf_rne(c.z * QSCALE);
            tmp.u[7] = f2bf_rne(c.w * QSCALE);
            qb[kc] = tmp.v;
        }
    }

    const int it_full = (vl == 0) ? NKT : ((vl + BC - 1) >> 6);
    const int nmax    = (it_full + 1) >> 1;   // block-uniform loop count

    // ---- prefetch registers (per group: one 64x64 K and V tile) ----
    float4 kf[4];
    float  vf[2][8];

    // V slot permutation (r9): slot ko*8+j holds key kb+((j>>2)<<5)+(j&3),
    // kb = (ko>>2)*16 + (ko&3)*4
    auto load_tile = [&](int it) {
        const float4* kg = (const float4*)(k + boff + (size_t)it * BC * DIM);
        #pragma unroll
        for (int i = 0; i < 4; i++) kf[i] = kg[tg + 256 * i];
        const float* vgf = v + boff + (size_t)it * BC * DIM;
        #pragma unroll
        for (int i = 0; i < 2; i++) {
            int slot = tg + 256 * i;
            int d = slot & 63, ko = slot >> 6;
            int kb = (ko >> 2) * 16 + (ko & 3) * 4;
            #pragma unroll
            for (int j = 0; j < 8; j++) {
                int kk = kb + ((j >> 2) << 5) + (j & 3);
                vf[i][j] = vgf[(size_t)kk * DIM + d];
            }
        }
    };

    auto stage = [&]() {
        #pragma unroll
        for (int i = 0; i < 4; i++) {
            int idx = tg + 256 * i;
            int row = idx >> 4, c4 = idx & 15;
            uint2 w;
            w.x = pack2_trunc(kf[i].x, kf[i].y);
            w.y = pack2_trunc(kf[i].z, kf[i].w);
            *(uint2*)&Ksg[row * LSTR + c4 * 4] = w;
        }
        #pragma unroll
        for (int i = 0; i < 2; i++) {
            int slot = tg + 256 * i;
            int d = slot & 63, ko = slot >> 6;
            uint4 w;
            w.x = pack2_trunc(vf[i][0], vf[i][1]);
            w.y = pack2_trunc(vf[i][2], vf[i][3]);
            w.z = pack2_trunc(vf[i][4], vf[i][5]);
            w.w = pack2_trunc(vf[i][6], vf[i][7]);
            *(uint4*)&Vtg[d * LSTR + ko * 8] = w;
        }
    };

    float m_run = -INFINITY;
    float l_run = 0.f;                 // per-lane partial (reduced once at end)
    f32x4 acc[4];
    #pragma unroll
    for (int dt = 0; dt < 4; dt++) acc[dt] = (f32x4){0.f, 0.f, 0.f, 0.f};

    bool act = (gid < it_full);        // group 0 always; group 1 iff it_full>=2
    if (act) load_tile(gid);

    for (int j = 0; j < nmax; j++) {
        const int tile = gid + 2 * j;
        const bool act_next = (tile + 2) < it_full;

        __builtin_amdgcn_sched_barrier(0);
        __builtin_amdgcn_s_barrier();          // A: prior tile's LDS reads done
        __builtin_amdgcn_sched_barrier(0);

        if (act) stage();
        if (act_next) load_tile(tile + 2);     // vmcnt floats across barrier B

        __builtin_amdgcn_sched_barrier(0);
        asm volatile("s_waitcnt lgkmcnt(0)" ::: "memory");
        __builtin_amdgcn_s_barrier();          // B: staging visible (lgkm only)
        __builtin_amdgcn_sched_barrier(0);

        if (act) {
            // ---- S^T = K x Q^T ----
            f32x4 sc[4];
            #pragma unroll
            for (int kt = 0; kt < 4; kt++) {
                bf16x8 ka0 = *(const bf16x8*)&Ksg[(kt * 16 + li) * LSTR + QD * 8];
                bf16x8 ka1 = *(const bf16x8*)&Ksg[(kt * 16 + li) * LSTR + 32 + QD * 8];
                f32x4 c = (f32x4){0.f, 0.f, 0.f, 0.f};
                c = __builtin_amdgcn_mfma_f32_16x16x32_bf16(ka0, qb[0], c, 0, 0, 0);
                c = __builtin_amdgcn_mfma_f32_16x16x32_bf16(ka1, qb[1], c, 0, 0, 0);
                sc[kt] = c;
            }

            // ---- mask (boundary/invalid tiles only) ----
            const int kbase = tile * BC;
            if (kbase + BC > vl) {
                #pragma unroll
                for (int kt = 0; kt < 4; kt++)
                    #pragma unroll
                    for (int r = 0; r < 4; r++) {
                        int key = kbase + kt * 16 + QD * 4 + r;
                        if (key >= vl) sc[kt][r] = MASKED;
                    }
            }

            // ---- softmax: common path has ZERO cross-lane ops (r12) ----
            float mt = -INFINITY;                   // lane-local max
            #pragma unroll
            for (int kt = 0; kt < 4; kt++)
                #pragma unroll
                for (int r = 0; r < 4; r++) mt = fmaxf(mt, sc[kt][r]);

            if (!__all(mt - m_run <= THR)) {
                mt = fmaxf(mt, __shfl_xor(mt, 16, 64));
                mt = fmaxf(mt, __shfl_xor(mt, 32, 64));
                float mn = fmaxf(m_run, mt);
                float alpha = exp2f(m_run - mn);    // -inf first tile -> 0
                m_run = mn;
                l_run *= alpha;                     // per-lane partial: exact
                float a0 = __shfl(alpha, QD * 4 + 0, 64);
                float a1 = __shfl(alpha, QD * 4 + 1, 64);
                float a2 = __shfl(alpha, QD * 4 + 2, 64);
                float a3 = __shfl(alpha, QD * 4 + 3, 64);
                #pragma unroll
                for (int dt = 0; dt < 4; dt++) {
                    acc[dt][0] *= a0; acc[dt][1] *= a1;
                    acc[dt][2] *= a2; acc[dt][3] *= a3;
                }
            }

            // P in registers (slot permutation): pa0 = sc0,sc2; pa1 = sc1,sc3
            union { bf16x8 v; uint u[4]; } pa0u, pa1u;
            {
                float p00 = exp2f(sc[0][0] - m_run), p01 = exp2f(sc[0][1] - m_run);
                float p02 = exp2f(sc[0][2] - m_run), p03 = exp2f(sc[0][3] - m_run);
                float p10 = exp2f(sc[1][0] - m_run), p11 = exp2f(sc[1][1] - m_run);
                float p12 = exp2f(sc[1][2] - m_run), p13 = exp2f(sc[1][3] - m_run);
                float p20 = exp2f(sc[2][0] - m_run), p21 = exp2f(sc[2][1] - m_run);
                float p22 = exp2f(sc[2][2] - m_run), p23 = exp2f(sc[2][3] - m_run);
                float p30 = exp2f(sc[3][0] - m_run), p31 = exp2f(sc[3][1] - m_run);
                float p32 = exp2f(sc[3][2] - m_run), p33 = exp2f(sc[3][3] - m_run);
                l_run += ((p00 + p01) + (p02 + p03)) + ((p10 + p11) + (p12 + p13))
                       + ((p20 + p21) + (p22 + p23)) + ((p30 + p31) + (p32 + p33));
                pa0u.u[0] = pack2_trunc(p00, p01);
                pa0u.u[1] = pack2_trunc(p02, p03);
                pa0u.u[2] = pack2_trunc(p20, p21);
                pa0u.u[3] = pack2_trunc(p22, p23);
                pa1u.u[0] = pack2_trunc(p10, p11);
                pa1u.u[1] = pack2_trunc(p12, p13);
                pa1u.u[2] = pack2_trunc(p30, p31);
                pa1u.u[3] = pack2_trunc(p32, p33);
            }

            // ---- PV: O += P x V(slot-permuted) ----
            #pragma unroll
            for (int dt = 0; dt < 4; dt++) {
                bf16x8 vb0 = *(const bf16x8*)&Vtg[(dt * 16 + li) * LSTR + QD * 8];
                bf16x8 vb1 = *(const bf16x8*)&Vtg[(dt * 16 + li) * LSTR + 32 + QD * 8];
                acc[dt] = __builtin_amdgcn_mfma_f32_16x16x32_bf16(pa0u.v, vb0, acc[dt], 0, 0, 0);
                acc[dt] = __builtin_amdgcn_mfma_f32_16x16x32_bf16(pa1u.v, vb1, acc[dt], 0, 0, 0);
            }
        }
        act = act_next;
    }

    // ---- deferred l reduction (once): l for query li, uniform over QD ----
    l_run += __shfl_xor(l_run, 16, 64);
    l_run += __shfl_xor(l_run, 32, 64);

    // ---- in-block merge: group 1 -> LDS, group 0 combines & writes out ----
    __builtin_amdgcn_sched_barrier(0);
    __builtin_amdgcn_s_barrier();              // all loop LDS reads done
    __builtin_amdgcn_sched_barrier(0);

    char*   mb  = (char*)SB;
    float*  Ox  = (float*)mb;                  // [64][64] f32 = 16384 B
    float2* ml0 = (float2*)(mb + 16384);       // [64] (m,l) group 0
    float2* ml1 = (float2*)(mb + 16896);       // [64] (m,l) group 1

    if (gid == 1) {
        if (QD == 0) ml1[wg * 16 + li] = make_float2(m_run, l_run);
        #pragma unroll
        for (int dt = 0; dt < 4; dt++)
            #pragma unroll
            for (int r = 0; r < 4; r++)
                Ox[(wg * 16 + QD * 4 + r) * 64 + dt * 16 + li] = acc[dt][r];
    } else {
        if (QD == 0) ml0[wg * 16 + li] = make_float2(m_run, l_run);
    }

    __builtin_amdgcn_sched_barrier(0);
    asm volatile("s_waitcnt lgkmcnt(0)" ::: "memory");
    __builtin_amdgcn_s_barrier();
    __builtin_amdgcn_sched_barrier(0);

    if (gid == 0) {
        float* ob = out + boff + (size_t)q0 * DIM;
        #pragma unroll
        for (int r = 0; r < 4; r++) {
            int grow = wg * 16 + QD * 4 + r;
            float2 a = ml0[grow];
            float2 c = ml1[grow];
            // empty group 1 (it_full==1): c = (-inf, 0) -> w1 = exp2(-inf) = 0
            float M  = fmaxf(a.x, c.x);
            float w0 = exp2f(a.x - M);
            float w1 = exp2f(c.x - M);
            float inv = 1.f / (a.y * w0 + c.y * w1);
            w0 *= inv; w1 *= inv;
            #pragma unroll
            for (int dt = 0; dt < 4; dt++) {
                ob[(size_t)grow * DIM + dt * 16 + li] =
                    acc[dt][r] * w0 + Ox[grow * 64 + dt * 16 + li] * w1;
            }
        }
    }
}

extern "C" void kernel_launch(void* const* d_in, const int* in_sizes, int n_in,
                              void* d_out, int out_size, void* d_ws, size_t ws_size,
                              hipStream_t stream) {
    const float* q = (const float*)d_in[0];
    const float* k = (const float*)d_in[1];
    const float* v = (const float*)d_in[2];
    const int* valid_lens = (const int*)d_in[3];
    float* out = (float*)d_out;

    dim3 grid(BATCH * (SEQ / BQ));   // 64 x 16 = 1024 blocks
    dim3 block(512);                 // 8 waves = 2 independent 4-wave groups
    attn_dualgrp<<<grid, block, 0, stream>>>(q, k, v, valid_lens, out);
}

// Round 12
// 123.114 us; speedup vs baseline: 1.0940x; 1.0935x over previous
//
#include <hip/hip_runtime.h>
#include <math.h>

// DotProductAttention B=64,S=1024,D=64 fp32, bf16-MFMA flash attention.
// Round 14: isolate the chain-shortening on a SINGLE dispatch. Round-13's
// in-block fusion regressed (46->56us): s_barrier is workgroup-wide, so
// fusing split-K halves into one block lockstepped the two groups and
// destroyed the stream independence that made round-12 fast. Dead end.
// Re-reading round-12's win (52.2->46.2): it changed BOTH streams (split-K)
// AND the serial chain (lane-local defer predicate + deferred l-reduction =
// zero cross-lane ops in the common softmax path). The chain change alone
// on a single dispatch was never benched -- and every pure scheduling move
// (r3/r5) was null, so the chain is the likelier driver. Scored metric is
// TOTAL (~72us fixed + ~8us per extra dispatch + combine ~8us): a single
// dispatch at main<52 beats the standing best (r7: 52.2 main, 124.4 total).
// This kernel = r12's lean body (P-in-reg slot perm, lane-local defer THR=8,
// per-lane partial l reduced once at end, lgkm-only barrier B, sched_barrier
// fences) + r6 skewed decode, 1024 blocks, no workspace, no combine.
// Prediction: main 46-49 -> total 118-122 if chain was the driver; main ~52
// -> chain null, split-K streams were the driver, revert to 2-dispatch.

#define BATCH 64
#define SEQ   1024
#define DIM   64
#define BQ    64           // queries per block (4 waves x 16)
#define BC    64           // keys per iteration
#define NKT   (SEQ / BC)   // 16
#define LSTR  72           // LDS row stride in bf16 (144 B)
#define QSCALE 0.18033688011112442f   // 0.125 * log2(e)
#define MASKED -1.0e6f
#define THR    8.0f        // defer-rescale threshold (exp2 domain)

typedef __attribute__((ext_vector_type(8))) short bf16x8;
typedef __attribute__((ext_vector_type(4))) float f32x4;

__device__ __forceinline__ uint pack2_trunc(float lo, float hi) {
    // [bf16(hi) : bf16(lo)] by byte-select (truncation) — one v_perm_b32
    return __builtin_amdgcn_perm(__float_as_uint(hi), __float_as_uint(lo), 0x07060302);
}
__device__ __forceinline__ ushort f2bf_rne(float x) {
    uint u = __float_as_uint(x);
    return (ushort)((u + 0x7fffu + ((u >> 16) & 1u)) >> 16);
}

__global__ __launch_bounds__(256, 4) void attn_lean_single(
    const float* __restrict__ q, const float* __restrict__ k,
    const float* __restrict__ v, const int* __restrict__ valid_lens,
    float* __restrict__ out)
{
    __shared__ ushort Ks[BC * LSTR];   // [key][d]
    __shared__ ushort Vt[DIM * LSTR];  // [d][slot]  (slot = permuted key)

    const int t    = threadIdx.x;
    const int wave = t >> 6;
    const int wl   = t & 63;
    const int QD   = wl >> 4;          // quad 0..3
    const int li   = wl & 15;          // lane-in-quad 0..15
    // skewed decode (r6): co-resident blocks (blockIdx spacing 256 -> grp+4)
    // hit different batches -> per-CU vl mix balanced.
    const int g    = blockIdx.x;
    const int grp  = g >> 6;                  // 0..15 q-tile
    const int b    = ((g & 63) + grp) & 63;   // de-aliased batch
    const int q0   = grp * BQ;
    const int vl   = valid_lens[b];

    const size_t boff = (size_t)b * SEQ * DIM;

    // ---- Q fragments (B-operand), pre-scaled, in registers ----
    bf16x8 qb[2];
    {
        const float* qrow = q + boff + (size_t)(q0 + wave * 16 + li) * DIM + QD * 8;
        #pragma unroll
        for (int kc = 0; kc < 2; kc++) {
            float4 a = *(const float4*)(qrow + kc * 32);
            float4 c = *(const float4*)(qrow + kc * 32 + 4);
            union { bf16x8 v; ushort u[8]; } tmp;
            tmp.u[0] = f2bf_rne(a.x * QSCALE);
            tmp.u[1] = f2bf_rne(a.y * QSCALE);
            tmp.u[2] = f2bf_rne(a.z * QSCALE);
            tmp.u[3] = f2bf_rne(a.w * QSCALE);
            tmp.u[4] = f2bf_rne(c.x * QSCALE);
            tmp.u[5] = f2bf_rne(c.y * QSCALE);
            tmp.u[6] = f2bf_rne(c.z * QSCALE);
            tmp.u[7] = f2bf_rne(c.w * QSCALE);
            qb[kc] = tmp.v;
        }
    }

    const int it_max = (vl == 0) ? NKT : ((vl + BC - 1) >> 6);

    // ---- prefetch registers ----
    float4 kf[4];          // K tile: 4 coalesced float4 per thread
    float  vf[2][8];       // V gather: (d = lane, 8 slot-ordered keys) x 2

    // V slot permutation (r9): slot ko*8+j holds key kb+((j>>2)<<5)+(j&3),
    // kb = (ko>>2)*16 + (ko&3)*4  -> lane's 16 softmax values ARE its PV
    // A-fragments (pa0 = sc0,sc2; pa1 = sc1,sc3 packed); P never touches LDS.
    auto load_tile = [&](int it) {
        const float4* kg = (const float4*)(k + boff + (size_t)it * BC * DIM);
        #pragma unroll
        for (int i = 0; i < 4; i++) kf[i] = kg[t + 256 * i];
        const float* vgf = v + boff + (size_t)it * BC * DIM;
        #pragma unroll
        for (int i = 0; i < 2; i++) {
            int slot = t + 256 * i;
            int d = slot & 63, ko = slot >> 6;
            int kb = (ko >> 2) * 16 + (ko & 3) * 4;
            #pragma unroll
            for (int j = 0; j < 8; j++) {
                int kk = kb + ((j >> 2) << 5) + (j & 3);
                vf[i][j] = vgf[(size_t)kk * DIM + d];
            }
        }
    };

    auto stage = [&]() {
        #pragma unroll
        for (int i = 0; i < 4; i++) {
            int idx = t + 256 * i;
            int row = idx >> 4, c4 = idx & 15;
            uint2 w;
            w.x = pack2_trunc(kf[i].x, kf[i].y);
            w.y = pack2_trunc(kf[i].z, kf[i].w);
            *(uint2*)&Ks[row * LSTR + c4 * 4] = w;
        }
        #pragma unroll
        for (int i = 0; i < 2; i++) {
            int slot = t + 256 * i;
            int d = slot & 63, ko = slot >> 6;
            uint4 w;
            w.x = pack2_trunc(vf[i][0], vf[i][1]);
            w.y = pack2_trunc(vf[i][2], vf[i][3]);
            w.z = pack2_trunc(vf[i][4], vf[i][5]);
            w.w = pack2_trunc(vf[i][6], vf[i][7]);
            *(uint4*)&Vt[d * LSTR + ko * 8] = w;   // b128 row write
        }
    };

    float m_run = -INFINITY;
    float l_run = 0.f;                 // PER-LANE PARTIAL (reduced once at end)
    f32x4 acc[4];
    #pragma unroll
    for (int dt = 0; dt < 4; dt++) acc[dt] = (f32x4){0.f, 0.f, 0.f, 0.f};

    load_tile(0);

    for (int it = 0; it < it_max; it++) {
        __builtin_amdgcn_sched_barrier(0);
        __builtin_amdgcn_s_barrier();          // A: prior tile's LDS reads done
        __builtin_amdgcn_sched_barrier(0);

        stage();
        if (it + 1 < it_max) load_tile(it + 1);    // vmcnt floats across B

        __builtin_amdgcn_sched_barrier(0);
        asm volatile("s_waitcnt lgkmcnt(0)" ::: "memory");
        __builtin_amdgcn_s_barrier();          // B: staging visible (lgkm only)
        __builtin_amdgcn_sched_barrier(0);

        // ---- S^T = K x Q^T : rows = keys (QD*4+r), cols = queries (li) ----
        f32x4 sc[4];
        #pragma unroll
        for (int kt = 0; kt < 4; kt++) {
            bf16x8 ka0 = *(const bf16x8*)&Ks[(kt * 16 + li) * LSTR + QD * 8];
            bf16x8 ka1 = *(const bf16x8*)&Ks[(kt * 16 + li) * LSTR + 32 + QD * 8];
            f32x4 c = (f32x4){0.f, 0.f, 0.f, 0.f};
            c = __builtin_amdgcn_mfma_f32_16x16x32_bf16(ka0, qb[0], c, 0, 0, 0);
            c = __builtin_amdgcn_mfma_f32_16x16x32_bf16(ka1, qb[1], c, 0, 0, 0);
            sc[kt] = c;
        }

        // ---- mask (only boundary/invalid tiles pay per-element cost) ----
        const int kbase = it * BC;
        if (kbase + BC > vl) {
            #pragma unroll
            for (int kt = 0; kt < 4; kt++)
                #pragma unroll
                for (int r = 0; r < 4; r++) {
                    int key = kbase + kt * 16 + QD * 4 + r;
                    if (key >= vl) sc[kt][r] = MASKED;
                }
        }

        // ---- softmax: common path has ZERO cross-lane ops (r12) ----
        float mt = -INFINITY;                       // lane-local max
        #pragma unroll
        for (int kt = 0; kt < 4; kt++)
            #pragma unroll
            for (int r = 0; r < 4; r++) mt = fmaxf(mt, sc[kt][r]);

        if (!__all(mt - m_run <= THR)) {
            // rare rescale branch: full reduce + row-uniform alpha
            mt = fmaxf(mt, __shfl_xor(mt, 16, 64));
            mt = fmaxf(mt, __shfl_xor(mt, 32, 64));
            float mn = fmaxf(m_run, mt);
            float alpha = exp2f(m_run - mn);        // -inf first tile -> 0
            m_run = mn;
            l_run *= alpha;                         // per-lane partial: exact
            float a0 = __shfl(alpha, QD * 4 + 0, 64);
            float a1 = __shfl(alpha, QD * 4 + 1, 64);
            float a2 = __shfl(alpha, QD * 4 + 2, 64);
            float a3 = __shfl(alpha, QD * 4 + 3, 64);
            #pragma unroll
            for (int dt = 0; dt < 4; dt++) {
                acc[dt][0] *= a0; acc[dt][1] *= a1;
                acc[dt][2] *= a2; acc[dt][3] *= a3;
            }
        }

        // P in registers (slot permutation): pa0 = sc0,sc2; pa1 = sc1,sc3
        union { bf16x8 v; uint u[4]; } pa0u, pa1u;
        {
            float p00 = exp2f(sc[0][0] - m_run), p01 = exp2f(sc[0][1] - m_run);
            float p02 = exp2f(sc[0][2] - m_run), p03 = exp2f(sc[0][3] - m_run);
            float p10 = exp2f(sc[1][0] - m_run), p11 = exp2f(sc[1][1] - m_run);
            float p12 = exp2f(sc[1][2] - m_run), p13 = exp2f(sc[1][3] - m_run);
            float p20 = exp2f(sc[2][0] - m_run), p21 = exp2f(sc[2][1] - m_run);
            float p22 = exp2f(sc[2][2] - m_run), p23 = exp2f(sc[2][3] - m_run);
            float p30 = exp2f(sc[3][0] - m_run), p31 = exp2f(sc[3][1] - m_run);
            float p32 = exp2f(sc[3][2] - m_run), p33 = exp2f(sc[3][3] - m_run);
            l_run += ((p00 + p01) + (p02 + p03)) + ((p10 + p11) + (p12 + p13))
                   + ((p20 + p21) + (p22 + p23)) + ((p30 + p31) + (p32 + p33));
            pa0u.u[0] = pack2_trunc(p00, p01);
            pa0u.u[1] = pack2_trunc(p02, p03);
            pa0u.u[2] = pack2_trunc(p20, p21);
            pa0u.u[3] = pack2_trunc(p22, p23);
            pa1u.u[0] = pack2_trunc(p10, p11);
            pa1u.u[1] = pack2_trunc(p12, p13);
            pa1u.u[2] = pack2_trunc(p30, p31);
            pa1u.u[3] = pack2_trunc(p32, p33);
        }

        // ---- PV: O += P x V(slot-permuted), P straight from registers ----
        #pragma unroll
        for (int dt = 0; dt < 4; dt++) {
            bf16x8 vb0 = *(const bf16x8*)&Vt[(dt * 16 + li) * LSTR + QD * 8];
            bf16x8 vb1 = *(const bf16x8*)&Vt[(dt * 16 + li) * LSTR + 32 + QD * 8];
            acc[dt] = __builtin_amdgcn_mfma_f32_16x16x32_bf16(pa0u.v, vb0, acc[dt], 0, 0, 0);
            acc[dt] = __builtin_amdgcn_mfma_f32_16x16x32_bf16(pa1u.v, vb1, acc[dt], 0, 0, 0);
        }
    }

    // ---- deferred l reduction (once) + epilogue ----
    l_run += __shfl_xor(l_run, 16, 64);
    l_run += __shfl_xor(l_run, 32, 64);
    float invl = 1.0f / l_run;
    float i0 = __shfl(invl, QD * 4 + 0, 64);
    float i1 = __shfl(invl, QD * 4 + 1, 64);
    float i2 = __shfl(invl, QD * 4 + 2, 64);
    float i3 = __shfl(invl, QD * 4 + 3, 64);
    float* ob = out + boff + (size_t)q0 * DIM;
    const int rbase = wave * 16 + QD * 4;
    #pragma unroll
    for (int dt = 0; dt < 4; dt++) {
        int col = dt * 16 + li;
        ob[(size_t)(rbase + 0) * DIM + col] = acc[dt][0] * i0;
        ob[(size_t)(rbase + 1) * DIM + col] = acc[dt][1] * i1;
        ob[(size_t)(rbase + 2) * DIM + col] = acc[dt][2] * i2;
        ob[(size_t)(rbase + 3) * DIM + col] = acc[dt][3] * i3;
    }
}

extern "C" void kernel_launch(void* const* d_in, const int* in_sizes, int n_in,
                              void* d_out, int out_size, void* d_ws, size_t ws_size,
                              hipStream_t stream) {
    const float* q = (const float*)d_in[0];
    const float* k = (const float*)d_in[1];
    const float* v = (const float*)d_in[2];
    const int* valid_lens = (const int*)d_in[3];
    float* out = (float*)d_out;

    dim3 grid(BATCH * (SEQ / BQ));   // 64 x 16 = 1024 blocks
    dim3 block(256);
    attn_lean_single<<<grid, block, 0, stream>>>(q, k, v, valid_lens, out);
}

// Round 13
// 122.491 us; speedup vs baseline: 1.0996x; 1.0051x over previous
//
#include <hip/hip_runtime.h>
#include <math.h>

// DotProductAttention B=64,S=1024,D=64 fp32, bf16-MFMA flash attention.
// Round 15: double-buffered LDS, ONE barrier per iteration. Round-14 confirmed
// the serial-chain theory (cross-lane-free softmax: 52->46us main, total 123.1
// = new best, single dispatch). Remaining exposed serial region: the stage()
// window between barriers A and B — every wave does vmcnt-drain + 16 packs +
// 6 LDS writes with NO compute overlapping, then pays TWO wave-sync barriers
// per iter. Fix: 2 LDS buffers (2 x 18.4 = 36.9 KB; grid 1024 = 4 blocks/CU
// needs exactly this):
//   iter: issue load(it+1) -> compute tile it from buf[cur]
//         -> stage buf[cur^1] (vmcnt drains here, covered by ~1500cy compute)
//         -> lgkmcnt(0) + s_barrier (ONE)
// Writes go to the opposite buffer from all readers -> no hazard; reads of
// buf[cur] complete before the barrier, writes to buf[cur] next iter come
// after it. Removes ~500-700cy of the ~2400cy/block-iter serial path.
// Kept: P-in-reg slot perm (r9), lane-local defer THR=8 + deferred l (r12),
// skewed decode (r6), launch_bounds(256,4) (VGPR cap 128, no r1-style squeeze).

#define BATCH 64
#define SEQ   1024
#define DIM   64
#define BQ    64           // queries per block (4 waves x 16)
#define BC    64           // keys per iteration
#define NKT   (SEQ / BC)   // 16
#define LSTR  72           // LDS row stride in bf16 (144 B)
#define QSCALE 0.18033688011112442f   // 0.125 * log2(e)
#define MASKED -1.0e6f
#define THR    8.0f        // defer-rescale threshold (exp2 domain)
#define KVSZ   (BC * LSTR) // 4608 ushorts per K (or V) tile

typedef __attribute__((ext_vector_type(8))) short bf16x8;
typedef __attribute__((ext_vector_type(4))) float f32x4;

__device__ __forceinline__ uint pack2_trunc(float lo, float hi) {
    // [bf16(hi) : bf16(lo)] by byte-select (truncation) — one v_perm_b32
    return __builtin_amdgcn_perm(__float_as_uint(hi), __float_as_uint(lo), 0x07060302);
}
__device__ __forceinline__ ushort f2bf_rne(float x) {
    uint u = __float_as_uint(x);
    return (ushort)((u + 0x7fffu + ((u >> 16) & 1u)) >> 16);
}

__global__ __launch_bounds__(256, 4) void attn_lean_dbuf(
    const float* __restrict__ q, const float* __restrict__ k,
    const float* __restrict__ v, const int* __restrict__ valid_lens,
    float* __restrict__ out)
{
    // two buffers, each = Ks (4608) + Vt (4608) ushorts = 18432 B
    __shared__ ushort SB[2][2 * KVSZ];

    const int t    = threadIdx.x;
    const int wave = t >> 6;
    const int wl   = t & 63;
    const int QD   = wl >> 4;          // quad 0..3
    const int li   = wl & 15;          // lane-in-quad 0..15
    // skewed decode (r6): co-resident blocks (blockIdx spacing 256 -> grp+4)
    // hit different batches -> per-CU vl mix balanced.
    const int g    = blockIdx.x;
    const int grp  = g >> 6;                  // 0..15 q-tile
    const int b    = ((g & 63) + grp) & 63;   // de-aliased batch
    const int q0   = grp * BQ;
    const int vl   = valid_lens[b];

    const size_t boff = (size_t)b * SEQ * DIM;

    // ---- Q fragments (B-operand), pre-scaled, in registers ----
    bf16x8 qb[2];
    {
        const float* qrow = q + boff + (size_t)(q0 + wave * 16 + li) * DIM + QD * 8;
        #pragma unroll
        for (int kc = 0; kc < 2; kc++) {
            float4 a = *(const float4*)(qrow + kc * 32);
            float4 c = *(const float4*)(qrow + kc * 32 + 4);
            union { bf16x8 v; ushort u[8]; } tmp;
            tmp.u[0] = f2bf_rne(a.x * QSCALE);
            tmp.u[1] = f2bf_rne(a.y * QSCALE);
            tmp.u[2] = f2bf_rne(a.z * QSCALE);
            tmp.u[3] = f2bf_rne(a.w * QSCALE);
            tmp.u[4] = f2bf_rne(c.x * QSCALE);
            tmp.u[5] = f2bf_rne(c.y * QSCALE);
            tmp.u[6] = f2bf_rne(c.z * QSCALE);
            tmp.u[7] = f2bf_rne(c.w * QSCALE);
            qb[kc] = tmp.v;
        }
    }

    const int it_max = (vl == 0) ? NKT : ((vl + BC - 1) >> 6);

    // ---- prefetch registers ----
    float4 kf[4];          // K tile: 4 coalesced float4 per thread
    float  vf[2][8];       // V gather: (d = lane, 8 slot-ordered keys) x 2

    // V slot permutation (r9): slot ko*8+j holds key kb+((j>>2)<<5)+(j&3),
    // kb = (ko>>2)*16 + (ko&3)*4  -> lane's 16 softmax values ARE its PV
    // A-fragments (pa0 = sc0,sc2; pa1 = sc1,sc3 packed); P never touches LDS.
    auto load_tile = [&](int it) {
        const float4* kg = (const float4*)(k + boff + (size_t)it * BC * DIM);
        #pragma unroll
        for (int i = 0; i < 4; i++) kf[i] = kg[t + 256 * i];
        const float* vgf = v + boff + (size_t)it * BC * DIM;
        #pragma unroll
        for (int i = 0; i < 2; i++) {
            int slot = t + 256 * i;
            int d = slot & 63, ko = slot >> 6;
            int kb = (ko >> 2) * 16 + (ko & 3) * 4;
            #pragma unroll
            for (int j = 0; j < 8; j++) {
                int kk = kb + ((j >> 2) << 5) + (j & 3);
                vf[i][j] = vgf[(size_t)kk * DIM + d];
            }
        }
    };

    auto stage = [&](int buf) {
        ushort* Ksb = SB[buf];
        ushort* Vtb = SB[buf] + KVSZ;
        #pragma unroll
        for (int i = 0; i < 4; i++) {
            int idx = t + 256 * i;
            int row = idx >> 4, c4 = idx & 15;
            uint2 w;
            w.x = pack2_trunc(kf[i].x, kf[i].y);
            w.y = pack2_trunc(kf[i].z, kf[i].w);
            *(uint2*)&Ksb[row * LSTR + c4 * 4] = w;
        }
        #pragma unroll
        for (int i = 0; i < 2; i++) {
            int slot = t + 256 * i;
            int d = slot & 63, ko = slot >> 6;
            uint4 w;
            w.x = pack2_trunc(vf[i][0], vf[i][1]);
            w.y = pack2_trunc(vf[i][2], vf[i][3]);
            w.z = pack2_trunc(vf[i][4], vf[i][5]);
            w.w = pack2_trunc(vf[i][6], vf[i][7]);
            *(uint4*)&Vtb[d * LSTR + ko * 8] = w;   // b128 row write
        }
    };

    float m_run = -INFINITY;
    float l_run = 0.f;                 // per-lane partial (reduced once at end)
    f32x4 acc[4];
    #pragma unroll
    for (int dt = 0; dt < 4; dt++) acc[dt] = (f32x4){0.f, 0.f, 0.f, 0.f};

    // ---- prologue: tile 0 into buf 0 ----
    load_tile(0);
    stage(0);                                   // vmcnt drains at reg use
    __builtin_amdgcn_sched_barrier(0);
    asm volatile("s_waitcnt lgkmcnt(0)" ::: "memory");
    __builtin_amdgcn_s_barrier();
    __builtin_amdgcn_sched_barrier(0);

    int cur = 0;
    for (int it = 0; it < it_max; it++) {
        const bool more = (it + 1 < it_max);
        if (more) load_tile(it + 1);            // VMEM issued before compute

        const ushort* Ksb = SB[cur];
        const ushort* Vtb = SB[cur] + KVSZ;

        // ---- S^T = K x Q^T : rows = keys (QD*4+r), cols = queries (li) ----
        f32x4 sc[4];
        #pragma unroll
        for (int kt = 0; kt < 4; kt++) {
            bf16x8 ka0 = *(const bf16x8*)&Ksb[(kt * 16 + li) * LSTR + QD * 8];
            bf16x8 ka1 = *(const bf16x8*)&Ksb[(kt * 16 + li) * LSTR + 32 + QD * 8];
            f32x4 c = (f32x4){0.f, 0.f, 0.f, 0.f};
            c = __builtin_amdgcn_mfma_f32_16x16x32_bf16(ka0, qb[0], c, 0, 0, 0);
            c = __builtin_amdgcn_mfma_f32_16x16x32_bf16(ka1, qb[1], c, 0, 0, 0);
            sc[kt] = c;
        }

        // ---- mask (only boundary/invalid tiles pay per-element cost) ----
        const int kbase = it * BC;
        if (kbase + BC > vl) {
            #pragma unroll
            for (int kt = 0; kt < 4; kt++)
                #pragma unroll
                for (int r = 0; r < 4; r++) {
                    int key = kbase + kt * 16 + QD * 4 + r;
                    if (key >= vl) sc[kt][r] = MASKED;
                }
        }

        // ---- softmax: common path has ZERO cross-lane ops (r12) ----
        float mt = -INFINITY;                   // lane-local max
        #pragma unroll
        for (int kt = 0; kt < 4; kt++)
            #pragma unroll
            for (int r = 0; r < 4; r++) mt = fmaxf(mt, sc[kt][r]);

        if (!__all(mt - m_run <= THR)) {
            // rare rescale branch: full reduce + row-uniform alpha
            mt = fmaxf(mt, __shfl_xor(mt, 16, 64));
            mt = fmaxf(mt, __shfl_xor(mt, 32, 64));
            float mn = fmaxf(m_run, mt);
            float alpha = exp2f(m_run - mn);    // -inf first tile -> 0
            m_run = mn;
            l_run *= alpha;                     // per-lane partial: exact
            float a0 = __shfl(alpha, QD * 4 + 0, 64);
            float a1 = __shfl(alpha, QD * 4 + 1, 64);
            float a2 = __shfl(alpha, QD * 4 + 2, 64);
            float a3 = __shfl(alpha, QD * 4 + 3, 64);
            #pragma unroll
            for (int dt = 0; dt < 4; dt++) {
                acc[dt][0] *= a0; acc[dt][1] *= a1;
                acc[dt][2] *= a2; acc[dt][3] *= a3;
            }
        }

        // P in registers (slot permutation): pa0 = sc0,sc2; pa1 = sc1,sc3
        union { bf16x8 v; uint u[4]; } pa0u, pa1u;
        {
            float p00 = exp2f(sc[0][0] - m_run), p01 = exp2f(sc[0][1] - m_run);
            float p02 = exp2f(sc[0][2] - m_run), p03 = exp2f(sc[0][3] - m_run);
            float p10 = exp2f(sc[1][0] - m_run), p11 = exp2f(sc[1][1] - m_run);
            float p12 = exp2f(sc[1][2] - m_run), p13 = exp2f(sc[1][3] - m_run);
            float p20 = exp2f(sc[2][0] - m_run), p21 = exp2f(sc[2][1] - m_run);
            float p22 = exp2f(sc[2][2] - m_run), p23 = exp2f(sc[2][3] - m_run);
            float p30 = exp2f(sc[3][0] - m_run), p31 = exp2f(sc[3][1] - m_run);
            float p32 = exp2f(sc[3][2] - m_run), p33 = exp2f(sc[3][3] - m_run);
            l_run += ((p00 + p01) + (p02 + p03)) + ((p10 + p11) + (p12 + p13))
                   + ((p20 + p21) + (p22 + p23)) + ((p30 + p31) + (p32 + p33));
            pa0u.u[0] = pack2_trunc(p00, p01);
            pa0u.u[1] = pack2_trunc(p02, p03);
            pa0u.u[2] = pack2_trunc(p20, p21);
            pa0u.u[3] = pack2_trunc(p22, p23);
            pa1u.u[0] = pack2_trunc(p10, p11);
            pa1u.u[1] = pack2_trunc(p12, p13);
            pa1u.u[2] = pack2_trunc(p30, p31);
            pa1u.u[3] = pack2_trunc(p32, p33);
        }

        // ---- PV: O += P x V(slot-permuted), P straight from registers ----
        #pragma unroll
        for (int dt = 0; dt < 4; dt++) {
            bf16x8 vb0 = *(const bf16x8*)&Vtb[(dt * 16 + li) * LSTR + QD * 8];
            bf16x8 vb1 = *(const bf16x8*)&Vtb[(dt * 16 + li) * LSTR + 32 + QD * 8];
            acc[dt] = __builtin_amdgcn_mfma_f32_16x16x32_bf16(pa0u.v, vb0, acc[dt], 0, 0, 0);
            acc[dt] = __builtin_amdgcn_mfma_f32_16x16x32_bf16(pa1u.v, vb1, acc[dt], 0, 0, 0);
        }

        if (more) {
            stage(cur ^ 1);                     // write OTHER buffer; no hazard
            // ONE barrier per iter: my reads of buf[cur] are lgkm-drained by
            // MFMA consumption; stage writes drain with lgkmcnt(0); next
            // iter's writes to buf[cur] come after this barrier.
            __builtin_amdgcn_sched_barrier(0);
            asm volatile("s_waitcnt lgkmcnt(0)" ::: "memory");
            __builtin_amdgcn_s_barrier();
            __builtin_amdgcn_sched_barrier(0);
            cur ^= 1;
        }
    }

    // ---- deferred l reduction (once) + epilogue ----
    l_run += __shfl_xor(l_run, 16, 64);
    l_run += __shfl_xor(l_run, 32, 64);
    float invl = 1.0f / l_run;
    float i0 = __shfl(invl, QD * 4 + 0, 64);
    float i1 = __shfl(invl, QD * 4 + 1, 64);
    float i2 = __shfl(invl, QD * 4 + 2, 64);
    float i3 = __shfl(invl, QD * 4 + 3, 64);
    float* ob = out + boff + (size_t)q0 * DIM;
    const int rbase = wave * 16 + QD * 4;
    #pragma unroll
    for (int dt = 0; dt < 4; dt++) {
        int col = dt * 16 + li;
        ob[(size_t)(rbase + 0) * DIM + col] = acc[dt][0] * i0;
        ob[(size_t)(rbase + 1) * DIM + col] = acc[dt][1] * i1;
        ob[(size_t)(rbase + 2) * DIM + col] = acc[dt][2] * i2;
        ob[(size_t)(rbase + 3) * DIM + col] = acc[dt][3] * i3;
    }
}

extern "C" void kernel_launch(void* const* d_in, const int* in_sizes, int n_in,
                              void* d_out, int out_size, void* d_ws, size_t ws_size,
                              hipStream_t stream) {
    const float* q = (const float*)d_in[0];
    const float* k = (const float*)d_in[1];
    const float* v = (const float*)d_in[2];
    const int* valid_lens = (const int*)d_in[3];
    float* out = (float*)d_out;

    dim3 grid(BATCH * (SEQ / BQ));   // 64 x 16 = 1024 blocks
    dim3 block(256);
    attn_lean_dbuf<<<grid, block, 0, stream>>>(q, k, v, valid_lens, out);
}

// Round 14
// 118.628 us; speedup vs baseline: 1.1354x; 1.0326x over previous
//
#include <hip/hip_runtime.h>
#include <math.h>

// DotProductAttention B=64,S=1024,D=64 fp32, bf16-MFMA flash attention.
// Round 16: locality AND balance in one decode. r13's dbuf was neutral
// (46->48 main, noise) -> sync structure is fully hidden; the one counter
// that moved with the 52->46 win and never reverted is FETCH (17->100MB):
// the r6 skew that fixed vl-balance destroyed XCD locality (each batch's
// K/V now pulled from remote L2/L3/HBM at 500-900cy instead of local-L2
// ~200cy) -- direct stall inflation in a latency-bound kernel.
// New decode (observed mapping: block g -> XCD g&7, CU (g>>3)&31):
//   x=g&7, y=g>>3, r=y&31, s=y>>5, bb=(r+2s)&7, b=x+8*bb, qt=(r>>3)*4+s
// Bijective. (1) all 16 q-tiles of batch b land on XCD b&7 -> K/V
// L2-resident (expect FETCH ~20-35MB); (2) the 4 same-CU blocks (fixed r,
// s=0..3) get 4 DISTINCT batches -> per-CU vl mix kept.
// Body = round-14's proven best (46.1us main / 123.1 total): single-buffer
// 18.4KB, two barriers (A bare, B lgkm-only, vmcnt floats), P-in-reg slot
// perm, lane-local defer THR=8, per-lane partial l reduced once at end.

#define BATCH 64
#define SEQ   1024
#define DIM   64
#define BQ    64           // queries per block (4 waves x 16)
#define BC    64           // keys per iteration
#define NKT   (SEQ / BC)   // 16
#define LSTR  72           // LDS row stride in bf16 (144 B)
#define QSCALE 0.18033688011112442f   // 0.125 * log2(e)
#define MASKED -1.0e6f
#define THR    8.0f        // defer-rescale threshold (exp2 domain)

typedef __attribute__((ext_vector_type(8))) short bf16x8;
typedef __attribute__((ext_vector_type(4))) float f32x4;

__device__ __forceinline__ uint pack2_trunc(float lo, float hi) {
    // [bf16(hi) : bf16(lo)] by byte-select (truncation) — one v_perm_b32
    return __builtin_amdgcn_perm(__float_as_uint(hi), __float_as_uint(lo), 0x07060302);
}
__device__ __forceinline__ ushort f2bf_rne(float x) {
    uint u = __float_as_uint(x);
    return (ushort)((u + 0x7fffu + ((u >> 16) & 1u)) >> 16);
}

__global__ __launch_bounds__(256, 4) void attn_lean_local(
    const float* __restrict__ q, const float* __restrict__ k,
    const float* __restrict__ v, const int* __restrict__ valid_lens,
    float* __restrict__ out)
{
    __shared__ ushort Ks[BC * LSTR];   // [key][d]
    __shared__ ushort Vt[DIM * LSTR];  // [d][slot]  (slot = permuted key)

    const int t    = threadIdx.x;
    const int wave = t >> 6;
    const int wl   = t & 63;
    const int QD   = wl >> 4;          // quad 0..3
    const int li   = wl & 15;          // lane-in-quad 0..15

    // ---- XCD-local + CU-balanced decode (bijective on [0,1024)) ----
    // mapping assumption (validated r5/r9/r12 FETCH deltas): g -> XCD g&7,
    // CU-in-XCD (g>>3)&31.
    const int g    = blockIdx.x;
    const int x    = g & 7;            // XCD
    const int y    = g >> 3;
    const int r    = y & 31;           // CU within XCD
    const int s    = y >> 5;           // 0..3 (which resident slot)
    const int bb   = (r + 2 * s) & 7;
    const int b    = x + 8 * bb;       // batch: all its q-tiles on XCD x
    const int qt   = (r >> 3) * 4 + s; // 0..15
    const int q0   = qt * BQ;
    const int vl   = valid_lens[b];

    const size_t boff = (size_t)b * SEQ * DIM;

    // ---- Q fragments (B-operand), pre-scaled, in registers ----
    bf16x8 qb[2];
    {
        const float* qrow = q + boff + (size_t)(q0 + wave * 16 + li) * DIM + QD * 8;
        #pragma unroll
        for (int kc = 0; kc < 2; kc++) {
            float4 a = *(const float4*)(qrow + kc * 32);
            float4 c = *(const float4*)(qrow + kc * 32 + 4);
            union { bf16x8 v; ushort u[8]; } tmp;
            tmp.u[0] = f2bf_rne(a.x * QSCALE);
            tmp.u[1] = f2bf_rne(a.y * QSCALE);
            tmp.u[2] = f2bf_rne(a.z * QSCALE);
            tmp.u[3] = f2bf_rne(a.w * QSCALE);
            tmp.u[4] = f2bf_rne(c.x * QSCALE);
            tmp.u[5] = f2bf_rne(c.y * QSCALE);
            tmp.u[6] = f2bf_rne(c.z * QSCALE);
            tmp.u[7] = f2bf_rne(c.w * QSCALE);
            qb[kc] = tmp.v;
        }
    }

    const int it_max = (vl == 0) ? NKT : ((vl + BC - 1) >> 6);

    // ---- prefetch registers ----
    float4 kf[4];          // K tile: 4 coalesced float4 per thread
    float  vf[2][8];       // V gather: (d = lane, 8 slot-ordered keys) x 2

    // V slot permutation (r9): slot ko*8+j holds key kb+((j>>2)<<5)+(j&3),
    // kb = (ko>>2)*16 + (ko&3)*4  -> lane's 16 softmax values ARE its PV
    // A-fragments (pa0 = sc0,sc2; pa1 = sc1,sc3 packed); P never touches LDS.
    auto load_tile = [&](int it) {
        const float4* kg = (const float4*)(k + boff + (size_t)it * BC * DIM);
        #pragma unroll
        for (int i = 0; i < 4; i++) kf[i] = kg[t + 256 * i];
        const float* vgf = v + boff + (size_t)it * BC * DIM;
        #pragma unroll
        for (int i = 0; i < 2; i++) {
            int slot = t + 256 * i;
            int d = slot & 63, ko = slot >> 6;
            int kb = (ko >> 2) * 16 + (ko & 3) * 4;
            #pragma unroll
            for (int j = 0; j < 8; j++) {
                int kk = kb + ((j >> 2) << 5) + (j & 3);
                vf[i][j] = vgf[(size_t)kk * DIM + d];
            }
        }
    };

    auto stage = [&]() {
        #pragma unroll
        for (int i = 0; i < 4; i++) {
            int idx = t + 256 * i;
            int row = idx >> 4, c4 = idx & 15;
            uint2 w;
            w.x = pack2_trunc(kf[i].x, kf[i].y);
            w.y = pack2_trunc(kf[i].z, kf[i].w);
            *(uint2*)&Ks[row * LSTR + c4 * 4] = w;
        }
        #pragma unroll
        for (int i = 0; i < 2; i++) {
            int slot = t + 256 * i;
            int d = slot & 63, ko = slot >> 6;
            uint4 w;
            w.x = pack2_trunc(vf[i][0], vf[i][1]);
            w.y = pack2_trunc(vf[i][2], vf[i][3]);
            w.z = pack2_trunc(vf[i][4], vf[i][5]);
            w.w = pack2_trunc(vf[i][6], vf[i][7]);
            *(uint4*)&Vt[d * LSTR + ko * 8] = w;   // b128 row write
        }
    };

    float m_run = -INFINITY;
    float l_run = 0.f;                 // per-lane partial (reduced once at end)
    f32x4 acc[4];
    #pragma unroll
    for (int dt = 0; dt < 4; dt++) acc[dt] = (f32x4){0.f, 0.f, 0.f, 0.f};

    load_tile(0);

    for (int it = 0; it < it_max; it++) {
        __builtin_amdgcn_sched_barrier(0);
        __builtin_amdgcn_s_barrier();          // A: prior tile's LDS reads done
        __builtin_amdgcn_sched_barrier(0);

        stage();
        if (it + 1 < it_max) load_tile(it + 1);    // vmcnt floats across B

        __builtin_amdgcn_sched_barrier(0);
        asm volatile("s_waitcnt lgkmcnt(0)" ::: "memory");
        __builtin_amdgcn_s_barrier();          // B: staging visible (lgkm only)
        __builtin_amdgcn_sched_barrier(0);

        // ---- S^T = K x Q^T : rows = keys (QD*4+r), cols = queries (li) ----
        f32x4 sc[4];
        #pragma unroll
        for (int kt = 0; kt < 4; kt++) {
            bf16x8 ka0 = *(const bf16x8*)&Ks[(kt * 16 + li) * LSTR + QD * 8];
            bf16x8 ka1 = *(const bf16x8*)&Ks[(kt * 16 + li) * LSTR + 32 + QD * 8];
            f32x4 c = (f32x4){0.f, 0.f, 0.f, 0.f};
            c = __builtin_amdgcn_mfma_f32_16x16x32_bf16(ka0, qb[0], c, 0, 0, 0);
            c = __builtin_amdgcn_mfma_f32_16x16x32_bf16(ka1, qb[1], c, 0, 0, 0);
            sc[kt] = c;
        }

        // ---- mask (only boundary/invalid tiles pay per-element cost) ----
        const int kbase = it * BC;
        if (kbase + BC > vl) {
            #pragma unroll
            for (int kt = 0; kt < 4; kt++)
                #pragma unroll
                for (int r2 = 0; r2 < 4; r2++) {
                    int key = kbase + kt * 16 + QD * 4 + r2;
                    if (key >= vl) sc[kt][r2] = MASKED;
                }
        }

        // ---- softmax: common path has ZERO cross-lane ops (r12) ----
        float mt = -INFINITY;                   // lane-local max
        #pragma unroll
        for (int kt = 0; kt < 4; kt++)
            #pragma unroll
            for (int r2 = 0; r2 < 4; r2++) mt = fmaxf(mt, sc[kt][r2]);

        if (!__all(mt - m_run <= THR)) {
            // rare rescale branch: full reduce + row-uniform alpha
            mt = fmaxf(mt, __shfl_xor(mt, 16, 64));
            mt = fmaxf(mt, __shfl_xor(mt, 32, 64));
            float mn = fmaxf(m_run, mt);
            float alpha = exp2f(m_run - mn);    // -inf first tile -> 0
            m_run = mn;
            l_run *= alpha;                     // per-lane partial: exact
            float a0 = __shfl(alpha, QD * 4 + 0, 64);
            float a1 = __shfl(alpha, QD * 4 + 1, 64);
            float a2 = __shfl(alpha, QD * 4 + 2, 64);
            float a3 = __shfl(alpha, QD * 4 + 3, 64);
            #pragma unroll
            for (int dt = 0; dt < 4; dt++) {
                acc[dt][0] *= a0; acc[dt][1] *= a1;
                acc[dt][2] *= a2; acc[dt][3] *= a3;
            }
        }

        // P in registers (slot permutation): pa0 = sc0,sc2; pa1 = sc1,sc3
        union { bf16x8 v; uint u[4]; } pa0u, pa1u;
        {
            float p00 = exp2f(sc[0][0] - m_run), p01 = exp2f(sc[0][1] - m_run);
            float p02 = exp2f(sc[0][2] - m_run), p03 = exp2f(sc[0][3] - m_run);
            float p10 = exp2f(sc[1][0] - m_run), p11 = exp2f(sc[1][1] - m_run);
            float p12 = exp2f(sc[1][2] - m_run), p13 = exp2f(sc[1][3] - m_run);
            float p20 = exp2f(sc[2][0] - m_run), p21 = exp2f(sc[2][1] - m_run);
            float p22 = exp2f(sc[2][2] - m_run), p23 = exp2f(sc[2][3] - m_run);
            float p30 = exp2f(sc[3][0] - m_run), p31 = exp2f(sc[3][1] - m_run);
            float p32 = exp2f(sc[3][2] - m_run), p33 = exp2f(sc[3][3] - m_run);
            l_run += ((p00 + p01) + (p02 + p03)) + ((p10 + p11) + (p12 + p13))
                   + ((p20 + p21) + (p22 + p23)) + ((p30 + p31) + (p32 + p33));
            pa0u.u[0] = pack2_trunc(p00, p01);
            pa0u.u[1] = pack2_trunc(p02, p03);
            pa0u.u[2] = pack2_trunc(p20, p21);
            pa0u.u[3] = pack2_trunc(p22, p23);
            pa1u.u[0] = pack2_trunc(p10, p11);
            pa1u.u[1] = pack2_trunc(p12, p13);
            pa1u.u[2] = pack2_trunc(p30, p31);
            pa1u.u[3] = pack2_trunc(p32, p33);
        }

        // ---- PV: O += P x V(slot-permuted), P straight from registers ----
        #pragma unroll
        for (int dt = 0; dt < 4; dt++) {
            bf16x8 vb0 = *(const bf16x8*)&Vt[(dt * 16 + li) * LSTR + QD * 8];
            bf16x8 vb1 = *(const bf16x8*)&Vt[(dt * 16 + li) * LSTR + 32 + QD * 8];
            acc[dt] = __builtin_amdgcn_mfma_f32_16x16x32_bf16(pa0u.v, vb0, acc[dt], 0, 0, 0);
            acc[dt] = __builtin_amdgcn_mfma_f32_16x16x32_bf16(pa1u.v, vb1, acc[dt], 0, 0, 0);
        }
    }

    // ---- deferred l reduction (once) + epilogue ----
    l_run += __shfl_xor(l_run, 16, 64);
    l_run += __shfl_xor(l_run, 32, 64);
    float invl = 1.0f / l_run;
    float i0 = __shfl(invl, QD * 4 + 0, 64);
    float i1 = __shfl(invl, QD * 4 + 1, 64);
    float i2 = __shfl(invl, QD * 4 + 2, 64);
    float i3 = __shfl(invl, QD * 4 + 3, 64);
    float* ob = out + boff + (size_t)q0 * DIM;
    const int rbase = wave * 16 + QD * 4;
    #pragma unroll
    for (int dt = 0; dt < 4; dt++) {
        int col = dt * 16 + li;
        ob[(size_t)(rbase + 0) * DIM + col] = acc[dt][0] * i0;
        ob[(size_t)(rbase + 1) * DIM + col] = acc[dt][1] * i1;
        ob[(size_t)(rbase + 2) * DIM + col] = acc[dt][2] * i2;
        ob[(size_t)(rbase + 3) * DIM + col] = acc[dt][3] * i3;
    }
}

extern "C" void kernel_launch(void* const* d_in, const int* in_sizes, int n_in,
                              void* d_out, int out_size, void* d_ws, size_t ws_size,
                              hipStream_t stream) {
    const float* q = (const float*)d_in[0];
    const float* k = (const float*)d_in[1];
    const float* v = (const float*)d_in[2];
    const int* valid_lens = (const int*)d_in[3];
    float* out = (float*)d_out;

    dim3 grid(BATCH * (SEQ / BQ));   // 64 x 16 = 1024 blocks
    dim3 block(256);
    attn_lean_local<<<grid, block, 0, stream>>>(q, k, v, valid_lens, out);
}